// Round 3
// baseline (973.908 us; speedup 1.0000x reference)
//
#include <hip/hip_runtime.h>
#include <stdint.h>

#define M_DIM 4096
#define K_DIM 4096
#define N_DIM 11008
#define BM    128
#define BN    128
#define BK    64

typedef __attribute__((ext_vector_type(8))) _Float16 f16x8;
typedef __attribute__((ext_vector_type(4))) float    f32x4;

__global__ __launch_bounds__(256, 2) void wq_gemm(
    const float* __restrict__ x,      // fp32 (upcast fp16) [M,K]
    const int*   __restrict__ qw,     // int32 [N,K], values 0..15
    const float* __restrict__ scales, // fp32 [K/G, N]
    const float* __restrict__ zeros,  // fp32 [K/G, N] (scaled zeros)
    const float* __restrict__ bias,   // fp32 [N]
    float*       __restrict__ out)    // fp32 [M,N]
{
    __shared__ __align__(16) _Float16 As[BM * BK];
    __shared__ __align__(16) _Float16 Bs[BN * BK];

    const int tid  = threadIdx.x;
    const int lane = tid & 63;
    const int wid  = tid >> 6;
    const int wm   = wid >> 1;          // wave row (0..1)
    const int wn   = wid & 1;           // wave col (0..1)
    const int l15  = lane & 15;
    const int l4   = lane >> 4;

    const int m0 = blockIdx.y * BM;
    const int n0 = blockIdx.x * BN;

    f32x4 acc[4][4] = {};

    for (int kt = 0; kt < K_DIM / BK; ++kt) {
        const int k0 = kt * BK;

        // ---- stage A tile [BM][BK]: fp32 load, cvt to fp16, ds_write 16B ----
        #pragma unroll
        for (int i = 0; i < 4; ++i) {
            int ci  = i * 256 + tid;            // 8-element chunk index
            int row = ci >> 3;                  // 0..127
            int col = (ci & 7) * 8;             // 0..56
            const float* src = x + (size_t)(m0 + row) * K_DIM + k0 + col;
            float4 f0 = *(const float4*)src;
            float4 f1 = *(const float4*)(src + 4);
            union { _Float16 h[8]; uint4 v; } pk;
            pk.h[0] = (_Float16)f0.x; pk.h[1] = (_Float16)f0.y;
            pk.h[2] = (_Float16)f0.z; pk.h[3] = (_Float16)f0.w;
            pk.h[4] = (_Float16)f1.x; pk.h[5] = (_Float16)f1.y;
            pk.h[6] = (_Float16)f1.z; pk.h[7] = (_Float16)f1.w;
            *(uint4*)(As + ci * 8) = pk.v;
        }

        // ---- stage B tile [BN][BK]: int32 load, dequant, cvt fp16, ds_write ----
        const int g = k0 >> 7;                  // group index (G=128, BK=64)
        #pragma unroll
        for (int i = 0; i < 4; ++i) {
            int ci = i * 256 + tid;
            int nl = ci >> 3;                   // tile row (0..127)
            int kc = (ci & 7) * 8;              // col start
            const int* qrow = qw + (size_t)(n0 + nl) * K_DIM + k0 + kc;
            int4 q0 = *(const int4*)qrow;
            int4 q1 = *(const int4*)(qrow + 4);
            float s = scales[(size_t)g * N_DIM + n0 + nl];
            float z = zeros [(size_t)g * N_DIM + n0 + nl];
            union { _Float16 h[8]; uint4 v; } pk;
            pk.h[0] = (_Float16)((float)q0.x * s + z);
            pk.h[1] = (_Float16)((float)q0.y * s + z);
            pk.h[2] = (_Float16)((float)q0.z * s + z);
            pk.h[3] = (_Float16)((float)q0.w * s + z);
            pk.h[4] = (_Float16)((float)q1.x * s + z);
            pk.h[5] = (_Float16)((float)q1.y * s + z);
            pk.h[6] = (_Float16)((float)q1.z * s + z);
            pk.h[7] = (_Float16)((float)q1.w * s + z);
            *(uint4*)(Bs + ci * 8) = pk.v;
        }

        __syncthreads();

        // ---- MFMA: 2 K-slices of 32, 4x4 fragments per wave ----
        #pragma unroll
        for (int ks = 0; ks < 2; ++ks) {
            f16x8 a[4], b[4];
            #pragma unroll
            for (int m = 0; m < 4; ++m)
                a[m] = *(const f16x8*)(As + (wm * 64 + m * 16 + l15) * BK + ks * 32 + l4 * 8);
            #pragma unroll
            for (int n = 0; n < 4; ++n)
                b[n] = *(const f16x8*)(Bs + (wn * 64 + n * 16 + l15) * BK + ks * 32 + l4 * 8);
            #pragma unroll
            for (int m = 0; m < 4; ++m)
                #pragma unroll
                for (int n = 0; n < 4; ++n)
                    acc[m][n] = __builtin_amdgcn_mfma_f32_16x16x32_f16(
                        a[m], b[n], acc[m][n], 0, 0, 0);
        }

        __syncthreads();
    }

    // ---- epilogue: C/D layout col=lane&15, row=(lane>>4)*4+j ----
    #pragma unroll
    for (int n = 0; n < 4; ++n) {
        int col = n0 + wn * 64 + n * 16 + l15;
        float bv = bias[col];
        #pragma unroll
        for (int m = 0; m < 4; ++m) {
            int rbase = m0 + wm * 64 + m * 16 + l4 * 4;
            #pragma unroll
            for (int j = 0; j < 4; ++j) {
                out[(size_t)(rbase + j) * N_DIM + col] = acc[m][n][j] + bv;
            }
        }
    }
}

extern "C" void kernel_launch(void* const* d_in, const int* in_sizes, int n_in,
                              void* d_out, int out_size, void* d_ws, size_t ws_size,
                              hipStream_t stream) {
    const float* x  = (const float*)d_in[0];
    const int*   qw = (const int*)d_in[1];
    const float* sc = (const float*)d_in[2];
    const float* zr = (const float*)d_in[3];
    const float* bi = (const float*)d_in[4];
    float* o = (float*)d_out;

    dim3 grid(N_DIM / BN, M_DIM / BM);   // 86 x 32
    wq_gemm<<<grid, dim3(256), 0, stream>>>(x, qw, sc, zr, bi, o);
}

// Round 4
// 471.076 us; speedup vs baseline: 2.0674x; 2.0674x over previous
//
#include <hip/hip_runtime.h>
#include <stdint.h>

#define M_DIM 4096
#define K_DIM 4096
#define N_DIM 11008
#define KP    512              // packed words (8 elems) per K row
#define BM    128
#define BN    128
#define BK    64

#define QP_BYTES   (11008u * 512u * 4u)        // 22,544,384
#define XW_OFFSET  25165824u                   // 24 MB, aligned
#define XW_BYTES   (4096u * 4096u * 2u)        // 33,554,432
#define WS_NEEDED  (XW_OFFSET + XW_BYTES)      // 58,720,256

typedef __attribute__((ext_vector_type(8))) _Float16 f16x8;
typedef __attribute__((ext_vector_type(2))) _Float16 f16x2;
typedef __attribute__((ext_vector_type(4))) float    f32x4;

// ---------- pre-pass 1: qweight int32 [N][K] -> nibble-interleaved u32 [N][K/8] ----------
// bit layout (for 1-op unpack of fp16 pairs via 0x000F000F masks):
// [3:0]=e0 [7:4]=e2 [11:8]=e4 [15:12]=e6 [19:16]=e1 [23:20]=e3 [27:24]=e5 [31:28]=e7
__global__ void pack_qw(const int* __restrict__ qw, unsigned int* __restrict__ qp) {
    int stride = gridDim.x * blockDim.x;
    for (int i = blockIdx.x * blockDim.x + threadIdx.x; i < N_DIM * KP; i += stride) {
        const int* src = qw + (size_t)i * 8;
        int4 a = *(const int4*)src;
        int4 b = *(const int4*)(src + 4);
        unsigned int w = (unsigned)a.x | ((unsigned)a.z << 4) | ((unsigned)b.x << 8) | ((unsigned)b.z << 12)
                       | ((unsigned)a.y << 16) | ((unsigned)a.w << 20) | ((unsigned)b.y << 24) | ((unsigned)b.w << 28);
        qp[i] = w;
    }
}

// ---------- pre-pass 2: x fp32 -> fp16, 16B-slot XOR-pre-swizzled within 128B groups ----------
__global__ void cvt_x(const float* __restrict__ x, uint4* __restrict__ xw) {
    int stride = gridDim.x * blockDim.x;
    for (int i = blockIdx.x * blockDim.x + threadIdx.x; i < M_DIM * KP; i += stride) {
        int m  = i >> 9;                 // K/8 = 512 slots per row
        int sg = i & 511;
        const float* src = x + ((size_t)m << 12) + sg * 8;
        float4 f0 = *(const float4*)src;
        float4 f1 = *(const float4*)(src + 4);
        union { _Float16 h[8]; uint4 v; } pk;
        pk.h[0]=(_Float16)f0.x; pk.h[1]=(_Float16)f0.y;
        pk.h[2]=(_Float16)f0.z; pk.h[3]=(_Float16)f0.w;
        pk.h[4]=(_Float16)f1.x; pk.h[5]=(_Float16)f1.y;
        pk.h[6]=(_Float16)f1.z; pk.h[7]=(_Float16)f1.w;
        int dst = (sg & ~7) | ((sg & 7) ^ (m & 7));   // pre-swizzle so linear LDS copy is swizzled
        xw[((size_t)m << 9) + dst] = pk.v;
    }
}

// ---------- dequant 8 nibbles -> 4 fp16x2 (exact: (1024+e)-1024 then single-round fma) ----------
__device__ __forceinline__ uint4 dq8(unsigned int w, f16x2 s2, f16x2 z2) {
    const f16x2 k1024 = {(_Float16)1024.0f, (_Float16)1024.0f};
    union { f16x2 h; unsigned int u; } p0, p1, p2, p3;
    p0.u = 0x64006400u | (w & 0x000F000Fu);
    p1.u = 0x64006400u | ((w >> 4)  & 0x000F000Fu);
    p2.u = 0x64006400u | ((w >> 8)  & 0x000F000Fu);
    p3.u = 0x64006400u | ((w >> 12) & 0x000F000Fu);
    union { f16x2 h2[4]; uint4 v; } r;
    r.h2[0] = (p0.h - k1024) * s2 + z2;
    r.h2[1] = (p1.h - k1024) * s2 + z2;
    r.h2[2] = (p2.h - k1024) * s2 + z2;
    r.h2[3] = (p3.h - k1024) * s2 + z2;
    return r.v;
}

// ---------- main GEMM: packed weights, swizzled LDS, global_load_lds A ----------
__global__ __launch_bounds__(256, 3) void wq_gemm_packed(
    const uint4*  __restrict__ xw,     // fp16 [M][512] 16B slots, pre-swizzled
    const uint4*  __restrict__ qp4,    // packed u32 [N][512] viewed as uint4 [N][128]
    const float*  __restrict__ scales, // fp32 [32][N]
    const float*  __restrict__ zeros,  // fp32 [32][N]
    const float*  __restrict__ bias,   // fp32 [N]
    float*        __restrict__ out)    // fp32 [M][N]
{
    __shared__ __align__(16) unsigned short As[BM * BK];
    __shared__ __align__(16) unsigned short Bs[BN * BK];

    const int tid  = threadIdx.x;
    const int lane = tid & 63;
    const int wid  = tid >> 6;
    const int wm   = wid >> 1;
    const int wn   = wid & 1;
    const int l15  = lane & 15;
    const int l4   = lane >> 4;

    const int m0 = blockIdx.y * BM;
    const int n0 = blockIdx.x * BN;

    const int brow  = tid >> 1;        // B-staging: row this thread dequantizes
    const int bhalf = tid & 1;         // which 4 of the 8 slots

    f32x4 acc[4][4] = {};

    for (int g = 0; g < 32; ++g) {     // group loop (G=128 = 2 K-tiles)
        float s = scales[(size_t)g * N_DIM + n0 + brow];
        float z = zeros [(size_t)g * N_DIM + n0 + brow];
        f16x2 s2 = {(_Float16)s, (_Float16)s};
        f16x2 z2 = {(_Float16)z, (_Float16)z};

        #pragma unroll
        for (int half = 0; half < 2; ++half) {
            const int kt  = g * 2 + half;
            const int kw0 = kt * 8;            // 16B-slot index base of this K-tile

            // A: 4x global_load_lds (16B/lane), source pre-swizzled so LDS is swizzled
            #pragma unroll
            for (int i = 0; i < 4; ++i) {
                int off16 = i * 256 + tid;
                int row   = off16 >> 3;
                int sl    = off16 & 7;
                const uint4* gsrc = xw + (size_t)(m0 + row) * KP + kw0 + sl;
                __builtin_amdgcn_global_load_lds(
                    (const __attribute__((address_space(1))) unsigned int*)gsrc,
                    (__attribute__((address_space(3))) unsigned int*)((char*)As + off16 * 16),
                    16, 0, 0);
            }

            // B: 16B packed load (32 weights), dequant, swizzled ds_write
            uint4 qword = qp4[(size_t)(n0 + brow) * 128 + kt * 2 + bhalf];
            #pragma unroll
            for (int j = 0; j < 4; ++j) {
                unsigned int w = (j == 0) ? qword.x : (j == 1) ? qword.y : (j == 2) ? qword.z : qword.w;
                int sl = (bhalf * 4 + j) ^ (brow & 7);
                *(uint4*)((char*)Bs + brow * 128 + sl * 16) = dq8(w, s2, z2);
            }

            __syncthreads();

            // MFMA: fragment reads with XOR-deswizzle
            #pragma unroll
            for (int ks = 0; ks < 2; ++ks) {
                f16x8 a[4], b[4];
                #pragma unroll
                for (int m = 0; m < 4; ++m) {
                    int row = wm * 64 + m * 16 + l15;
                    int sl  = (ks * 4 + l4) ^ (row & 7);
                    a[m] = *(const f16x8*)((char*)As + row * 128 + sl * 16);
                }
                #pragma unroll
                for (int n = 0; n < 4; ++n) {
                    int row = wn * 64 + n * 16 + l15;
                    int sl  = (ks * 4 + l4) ^ (row & 7);
                    b[n] = *(const f16x8*)((char*)Bs + row * 128 + sl * 16);
                }
                #pragma unroll
                for (int m = 0; m < 4; ++m)
                    #pragma unroll
                    for (int n = 0; n < 4; ++n)
                        acc[m][n] = __builtin_amdgcn_mfma_f32_16x16x32_f16(
                            a[m], b[n], acc[m][n], 0, 0, 0);
            }

            __syncthreads();
        }
    }

    #pragma unroll
    for (int n = 0; n < 4; ++n) {
        int col = n0 + wn * 64 + n * 16 + l15;
        float bv = bias[col];
        #pragma unroll
        for (int m = 0; m < 4; ++m) {
            int rbase = m0 + wm * 64 + m * 16 + l4 * 4;
            #pragma unroll
            for (int j = 0; j < 4; ++j)
                out[(size_t)(rbase + j) * N_DIM + col] = acc[m][n][j] + bv;
        }
    }
}

// ---------- fallback (round-3 proven kernel) if ws too small ----------
__global__ __launch_bounds__(256, 2) void wq_gemm_fb(
    const float* __restrict__ x, const int* __restrict__ qw,
    const float* __restrict__ scales, const float* __restrict__ zeros,
    const float* __restrict__ bias, float* __restrict__ out)
{
    __shared__ __align__(16) _Float16 As[BM * BK];
    __shared__ __align__(16) _Float16 Bs[BN * BK];
    const int tid = threadIdx.x, lane = tid & 63, wid = tid >> 6;
    const int wm = wid >> 1, wn = wid & 1, l15 = lane & 15, l4 = lane >> 4;
    const int m0 = blockIdx.y * BM, n0 = blockIdx.x * BN;
    f32x4 acc[4][4] = {};
    for (int kt = 0; kt < K_DIM / BK; ++kt) {
        const int k0 = kt * BK;
        #pragma unroll
        for (int i = 0; i < 4; ++i) {
            int ci = i * 256 + tid, row = ci >> 3, col = (ci & 7) * 8;
            const float* src = x + (size_t)(m0 + row) * K_DIM + k0 + col;
            float4 f0 = *(const float4*)src; float4 f1 = *(const float4*)(src + 4);
            union { _Float16 h[8]; uint4 v; } pk;
            pk.h[0]=(_Float16)f0.x; pk.h[1]=(_Float16)f0.y; pk.h[2]=(_Float16)f0.z; pk.h[3]=(_Float16)f0.w;
            pk.h[4]=(_Float16)f1.x; pk.h[5]=(_Float16)f1.y; pk.h[6]=(_Float16)f1.z; pk.h[7]=(_Float16)f1.w;
            *(uint4*)(As + ci * 8) = pk.v;
        }
        const int g = k0 >> 7;
        #pragma unroll
        for (int i = 0; i < 4; ++i) {
            int ci = i * 256 + tid, nl = ci >> 3, kc = (ci & 7) * 8;
            const int* qrow = qw + (size_t)(n0 + nl) * K_DIM + k0 + kc;
            int4 q0 = *(const int4*)qrow; int4 q1 = *(const int4*)(qrow + 4);
            float s = scales[(size_t)g * N_DIM + n0 + nl];
            float z = zeros [(size_t)g * N_DIM + n0 + nl];
            union { _Float16 h[8]; uint4 v; } pk;
            pk.h[0]=(_Float16)((float)q0.x*s+z); pk.h[1]=(_Float16)((float)q0.y*s+z);
            pk.h[2]=(_Float16)((float)q0.z*s+z); pk.h[3]=(_Float16)((float)q0.w*s+z);
            pk.h[4]=(_Float16)((float)q1.x*s+z); pk.h[5]=(_Float16)((float)q1.y*s+z);
            pk.h[6]=(_Float16)((float)q1.z*s+z); pk.h[7]=(_Float16)((float)q1.w*s+z);
            *(uint4*)(Bs + ci * 8) = pk.v;
        }
        __syncthreads();
        #pragma unroll
        for (int ks = 0; ks < 2; ++ks) {
            f16x8 a[4], b[4];
            #pragma unroll
            for (int m = 0; m < 4; ++m)
                a[m] = *(const f16x8*)(As + (wm*64 + m*16 + l15) * BK + ks*32 + l4*8);
            #pragma unroll
            for (int n = 0; n < 4; ++n)
                b[n] = *(const f16x8*)(Bs + (wn*64 + n*16 + l15) * BK + ks*32 + l4*8);
            #pragma unroll
            for (int m = 0; m < 4; ++m)
                #pragma unroll
                for (int n = 0; n < 4; ++n)
                    acc[m][n] = __builtin_amdgcn_mfma_f32_16x16x32_f16(a[m], b[n], acc[m][n], 0, 0, 0);
        }
        __syncthreads();
    }
    #pragma unroll
    for (int n = 0; n < 4; ++n) {
        int col = n0 + wn * 64 + n * 16 + l15;
        float bv = bias[col];
        #pragma unroll
        for (int m = 0; m < 4; ++m) {
            int rbase = m0 + wm * 64 + m * 16 + l4 * 4;
            #pragma unroll
            for (int j = 0; j < 4; ++j)
                out[(size_t)(rbase + j) * N_DIM + col] = acc[m][n][j] + bv;
        }
    }
}

extern "C" void kernel_launch(void* const* d_in, const int* in_sizes, int n_in,
                              void* d_out, int out_size, void* d_ws, size_t ws_size,
                              hipStream_t stream) {
    const float* x  = (const float*)d_in[0];
    const int*   qw = (const int*)d_in[1];
    const float* sc = (const float*)d_in[2];
    const float* zr = (const float*)d_in[3];
    const float* bi = (const float*)d_in[4];
    float* o = (float*)d_out;

    dim3 grid(N_DIM / BN, M_DIM / BM);   // 86 x 32

    if (ws_size >= WS_NEEDED) {
        unsigned int* qp = (unsigned int*)d_ws;
        uint4* xw = (uint4*)((char*)d_ws + XW_OFFSET);
        pack_qw<<<2048, 256, 0, stream>>>(qw, qp);
        cvt_x  <<<2048, 256, 0, stream>>>(x, xw);
        wq_gemm_packed<<<grid, dim3(256), 0, stream>>>((const uint4*)xw, (const uint4*)qp, sc, zr, bi, o);
    } else {
        wq_gemm_fb<<<grid, dim3(256), 0, stream>>>(x, qw, sc, zr, bi, o);
    }
}